// Round 10
// baseline (317.547 us; speedup 1.0000x reference)
//
#include <hip/hip_runtime.h>
#include <hip/hip_bf16.h>

#define NN 4096
#define DD 128
#define NS 75
#define TOT (NN * NN)

// k_d2 tiling
#define BT 128
#define KCC 32
#define NBD2 (NN / BT)                      // 32
#define GRID_D2 (NBD2 * (NBD2 + 1) / 2)     // 528

// sweep tiling: 64x64 tiles, 256 threads, 16 elems/thread streamed per chunk
#define SB 64
#define NBSW (NN / SB)                      // 64
#define GRID_SW (NBSW * (NBSW + 1) / 2)     // 2080

typedef float v2f __attribute__((ext_vector_type(2)));

__device__ __forceinline__ float fexp2(float v) { return __builtin_amdgcn_exp2f(v); }

// linear index -> (bi, bj) with bi <= bj, row-major over upper triangle
__device__ __forceinline__ void tri_decode(int t, int nb, int& bi, int& bj) {
    int b = 0, rem = t;
    while (rem >= nb - b) { rem -= nb - b; ++b; }   // uniform across block -> scalar
    bi = b; bj = b + rem;
}

// ---------------- ws layout (bytes) ----------------
// 0                       : double dist_sum
// 8                       : unsigned long long nz_count
// 16                      : double KL[NS]
// 16 + 8*NS               : double KK[NS]
// 16 + 16*NS              : float sq[NN]
// 16 + 16*NS + 4*NN       : float csig[NS]   (log2e / sigma_s^2)
// 16 + 16*NS + 4*NN + 4*NS: float copt

__global__ void k_rowsq(const float* __restrict__ x, float* __restrict__ sq,
                        double* __restrict__ dsum, unsigned long long* __restrict__ nzc) {
    int tid = blockIdx.x * blockDim.x + threadIdx.x;
    if (tid == 0) { *dsum = 0.0; *nzc = 0ull; }
    if (tid < NN) {
        const float4* row = (const float4*)(x + (size_t)tid * DD);
        float s = 0.f;
#pragma unroll
        for (int i = 0; i < DD / 4; ++i) {
            float4 v = row[i];
            s += v.x * v.x + v.y * v.y + v.z * v.z + v.w * v.w;
        }
        sq[tid] = s;
    }
}

// 128x128 output tile per block, upper-triangle grid, mirrored writes.
__launch_bounds__(256)
__global__ void k_d2(const float* __restrict__ x, const float* __restrict__ sq,
                     float* __restrict__ d2, double* __restrict__ dsum,
                     unsigned long long* __restrict__ nzc) {
    __shared__ float at[KCC][BT + 4];   // stride 132: 16B-aligned b128 reads, writes 4-way max
    __shared__ float btl[KCC][BT + 4];
    __shared__ double red_d[4];
    __shared__ int red_n[4];

    int bi, bj;
    tri_decode(blockIdx.x, NBD2, bi, bj);
    const int r0 = bi * BT, c0 = bj * BT;
    const int tid = threadIdx.x;
    const int tx = tid & 31;   // col group: 4 cols
    const int ty = tid >> 5;   // row group: 16 rows

    float acc[16][4];
#pragma unroll
    for (int r = 0; r < 16; ++r)
#pragma unroll
        for (int c = 0; c < 4; ++c) acc[r][c] = 0.f;

    for (int kb = 0; kb < DD; kb += KCC) {
#pragma unroll
        for (int i = 0; i < 4; ++i) {
            int idx = tid + 256 * i;       // 0..1023
            int row = idx >> 3;            // 0..127
            int k4 = (idx & 7) * 4;        // 0..28
            float4 va = *(const float4*)(x + (size_t)(r0 + row) * DD + kb + k4);
            at[k4 + 0][row] = va.x; at[k4 + 1][row] = va.y;
            at[k4 + 2][row] = va.z; at[k4 + 3][row] = va.w;
            float4 vb = *(const float4*)(x + (size_t)(c0 + row) * DD + kb + k4);
            btl[k4 + 0][row] = vb.x; btl[k4 + 1][row] = vb.y;
            btl[k4 + 2][row] = vb.z; btl[k4 + 3][row] = vb.w;
        }
        __syncthreads();
#pragma unroll
        for (int kk = 0; kk < KCC; ++kk) {
            float av[16];
            *(float4*)&av[0]  = *(const float4*)&at[kk][ty * 16 + 0];
            *(float4*)&av[4]  = *(const float4*)&at[kk][ty * 16 + 4];
            *(float4*)&av[8]  = *(const float4*)&at[kk][ty * 16 + 8];
            *(float4*)&av[12] = *(const float4*)&at[kk][ty * 16 + 12];
            float4 b4 = *(const float4*)&btl[kk][tx * 4];
            float bv[4] = {b4.x, b4.y, b4.z, b4.w};
#pragma unroll
            for (int r = 0; r < 16; ++r)
#pragma unroll
                for (int c = 0; c < 4; ++c)
                    acc[r][c] = fmaf(av[r], bv[c], acc[r][c]);
        }
        __syncthreads();
    }

    float sqi[16], sqj[4];
#pragma unroll
    for (int r = 0; r < 16; ++r) sqi[r] = sq[r0 + ty * 16 + r];
#pragma unroll
    for (int c = 0; c < 4; ++c) sqj[c] = sq[c0 + tx * 4 + c];

    float myd = 0.f;
    int myn = 0;
#pragma unroll
    for (int r = 0; r < 16; ++r) {
#pragma unroll
        for (int c = 0; c < 4; ++c) {
            float v = fmaxf(sqi[r] + sqj[c] - 2.f * acc[r][c], 0.f);
            acc[r][c] = v;
            if (v > 0.f) { myd += sqrtf(v); ++myn; }
        }
        float4 o = {acc[r][0], acc[r][1], acc[r][2], acc[r][3]};
        *(float4*)(d2 + (size_t)(r0 + ty * 16 + r) * NN + c0 + tx * 4) = o;
    }
    if (bi != bj) {
#pragma unroll
        for (int c = 0; c < 4; ++c) {
            size_t base = (size_t)(c0 + tx * 4 + c) * NN + r0 + ty * 16;
            float4 w0 = {acc[0][c],  acc[1][c],  acc[2][c],  acc[3][c]};
            float4 w1 = {acc[4][c],  acc[5][c],  acc[6][c],  acc[7][c]};
            float4 w2 = {acc[8][c],  acc[9][c],  acc[10][c], acc[11][c]};
            float4 w3 = {acc[12][c], acc[13][c], acc[14][c], acc[15][c]};
            *(float4*)(d2 + base + 0)  = w0;
            *(float4*)(d2 + base + 4)  = w1;
            *(float4*)(d2 + base + 8)  = w2;
            *(float4*)(d2 + base + 12) = w3;
        }
    }

    const int w = (bi == bj) ? 1 : 2;
    double dd_ = (double)myd;
#pragma unroll
    for (int off = 32; off > 0; off >>= 1) {
        dd_ += __shfl_down(dd_, off);
        myn += __shfl_down(myn, off);
    }
    int wave = tid >> 6;
    if ((tid & 63) == 0) { red_d[wave] = dd_; red_n[wave] = myn; }
    __syncthreads();
    if (tid == 0) {
        double td = red_d[0] + red_d[1] + red_d[2] + red_d[3];
        int tn = red_n[0] + red_n[1] + red_n[2] + red_n[3];
        atomicAdd(dsum, td * (double)w);
        atomicAdd(nzc, (unsigned long long)(tn * w));
    }
}

__global__ void k_sigmas(const double* __restrict__ dsum, const unsigned long long* __restrict__ nzc,
                         float* __restrict__ csig, double* __restrict__ KL, double* __restrict__ KK) {
    int t = threadIdx.x;
    float mean = (float)(*dsum / (double)(*nzc));
    float lo = 0.1f * mean;
    float hi = 10.0f * mean;
    float step = (hi - lo) / (float)NS;
    if (t < NS) {
        float s = lo + step * (float)t;
        csig[t] = (float)(1.4426950408889634 / ((double)s * (double)s));
        KL[t] = 0.0;
        KK[t] = 0.0;
    }
}

// Sweep v7: occupancy-first. __launch_bounds__(256, 8) caps the UNIFIED
// register allocation at 64/wave -> 32 waves/CU (R4-R9 forensics: reported
// VGPR_Count is arch-only; real allocation was ~120, capping occupancy at
// ~17 waves/CU = the measured 53%). CH=5 sigma-chunks keep the live set
// ~50 regs: acc 20 + c 5 + one row's data 8 + addressing. Data is reloaded
// from L2/L3 each chunk (memory clobber stops hoisting); 15 passes over the
// 134 MB working set ride the trans-pipe time.
template <int CH, int NCHUNK>
__launch_bounds__(256, 8)
__global__ void k_sweep_all(const float* __restrict__ d2, const float* __restrict__ lk,
                            const float* __restrict__ csig, double* __restrict__ KL,
                            double* __restrict__ KK) {
    int bi, bj;
    tri_decode(blockIdx.x, NBSW, bi, bj);
    const int r0 = bi * SB, c0 = bj * SB;
    const float w = (bi == bj) ? 1.f : 2.f;

    const int rr = threadIdx.x >> 4;          // 0..15
    const int c4 = (threadIdx.x & 15) * 4;    // 0..60
    const size_t base = (size_t)(r0 + rr) * NN + c0 + c4;

    __shared__ double part[4][2 * CH * NCHUNK];
    const int lane = threadIdx.x & 63, wave = threadIdx.x >> 6;

#pragma unroll 1
    for (int ch = 0; ch < NCHUNK; ++ch) {
        asm volatile("" ::: "memory");        // forbid hoisting loads across chunks
        const int s0 = ch * CH;
        float c[CH];
#pragma unroll
        for (int s = 0; s < CH; ++s) c[s] = csig[s0 + s];   // uniform -> SGPR
        v2f akl[CH], akk[CH];
#pragma unroll
        for (int s = 0; s < CH; ++s) { akl[s] = (v2f){0.f, 0.f}; akk[s] = (v2f){0.f, 0.f}; }

#pragma unroll
        for (int it = 0; it < 4; ++it) {
            size_t off = base + (size_t)(16 * it) * NN;
            float4 dv = *(const float4*)(d2 + off);
            float4 lv = *(const float4*)(lk + off);
            v2f nd0 = (v2f){-dv.x, -dv.y}, nd1 = (v2f){-dv.z, -dv.w};
            v2f l0  = (v2f){lv.x, lv.y},  l1  = (v2f){lv.z, lv.w};
#pragma unroll
            for (int s = 0; s < CH; ++s) {
                v2f a0 = nd0 * c[s];                                // v_pk_mul_f32
                v2f K0 = {fexp2(a0.x), fexp2(a0.y)};                // 2x v_exp_f32
                akl[s] = __builtin_elementwise_fma(K0, l0, akl[s]); // v_pk_fma_f32
                akk[s] = __builtin_elementwise_fma(K0, K0, akk[s]);
                v2f a1 = nd1 * c[s];
                v2f K1 = {fexp2(a1.x), fexp2(a1.y)};
                akl[s] = __builtin_elementwise_fma(K1, l1, akl[s]);
                akk[s] = __builtin_elementwise_fma(K1, K1, akk[s]);
            }
        }

#pragma unroll
        for (int s = 0; s < CH; ++s) {
            float v1 = akl[s].x + akl[s].y, v2 = akk[s].x + akk[s].y;
#pragma unroll
            for (int off = 32; off > 0; off >>= 1) {
                v1 += __shfl_down(v1, off);
                v2 += __shfl_down(v2, off);
            }
            if (lane == 0) {
                part[wave][2 * s0 + s]      = (double)(v1 * w);
                part[wave][2 * s0 + CH + s] = (double)(v2 * w);
            }
        }
    }
    __syncthreads();
    const int t = threadIdx.x;
    if (t < 2 * CH * NCHUNK) {
        double v = part[0][t] + part[1][t] + part[2][t] + part[3][t];
        const int ch = t / (2 * CH);          // compile-time divisor
        const int r  = t - ch * 2 * CH;
        if (r < CH) atomicAdd(&KL[ch * CH + r], v);
        else        atomicAdd(&KK[ch * CH + r - CH], v);
    }
}

__global__ void k_argmax(const double* __restrict__ KL, const double* __restrict__ KK,
                         const float* __restrict__ csig, float* __restrict__ copt) {
    if (threadIdx.x == 0 && blockIdx.x == 0) {
        double best = -1.0;
        int bi = 0;
        for (int i = 0; i < NS; ++i) {
            double loss = KL[i] / sqrt(KK[i]);
            if (loss > best) { best = loss; bi = i; }   // strict > keeps FIRST max (jnp.argmax)
        }
        *copt = csig[bi];
    }
}

__launch_bounds__(256)
__global__ void k_final(float* __restrict__ d2, const float* __restrict__ copt) {
    const float c = *copt;
    const float inv_n = 1.0f / (float)NN;
    const int nthreads = gridDim.x * blockDim.x;
    float4* p = (float4*)d2;
    for (int i = blockIdx.x * blockDim.x + threadIdx.x; i < TOT / 4; i += nthreads) {
        float4 v = p[i];
        v.x = fexp2(-v.x * c) * inv_n;
        v.y = fexp2(-v.y * c) * inv_n;
        v.z = fexp2(-v.z * c) * inv_n;
        v.w = fexp2(-v.w * c) * inv_n;
        p[i] = v;
    }
}

extern "C" void kernel_launch(void* const* d_in, const int* in_sizes, int n_in,
                              void* d_out, int out_size, void* d_ws, size_t ws_size,
                              hipStream_t stream) {
    const float* x  = (const float*)d_in[0];
    const float* lk = (const float*)d_in[1];
    float* out = (float*)d_out;   // doubles as the d2 buffer, transformed in place at the end
    char* ws = (char*)d_ws;

    double* dsum = (double*)(ws + 0);
    unsigned long long* nzc = (unsigned long long*)(ws + 8);
    double* KL = (double*)(ws + 16);
    double* KK = (double*)(ws + 16 + 8 * NS);
    float* sqv  = (float*)(ws + 16 + 16 * NS);
    float* csig = (float*)(ws + 16 + 16 * NS + 4 * NN);
    float* copt = (float*)(ws + 16 + 16 * NS + 4 * NN + 4 * NS);

    hipLaunchKernelGGL(k_rowsq, dim3(NN / 256), dim3(256), 0, stream, x, sqv, dsum, nzc);
    hipLaunchKernelGGL(k_d2, dim3(GRID_D2), dim3(256), 0, stream, x, sqv, out, dsum, nzc);
    hipLaunchKernelGGL(k_sigmas, dim3(1), dim3(128), 0, stream, dsum, nzc, csig, KL, KK);
    hipLaunchKernelGGL((k_sweep_all<5, 15>), dim3(GRID_SW), dim3(256), 0, stream, out, lk, csig, KL, KK);
    hipLaunchKernelGGL(k_argmax, dim3(1), dim3(64), 0, stream, KL, KK, csig, copt);
    hipLaunchKernelGGL(k_final, dim3(2048), dim3(256), 0, stream, out, copt);
}

// Round 11
// 189.546 us; speedup vs baseline: 1.6753x; 1.6753x over previous
//
#include <hip/hip_runtime.h>
#include <hip/hip_bf16.h>

#define NN 4096
#define DD 128
#define NS 75
#define TOT (NN * NN)

// k_d2 tiling
#define BT 128
#define KCC 32
#define NBD2 (NN / BT)                      // 32
#define GRID_D2 (NBD2 * (NBD2 + 1) / 2)     // 528

// sweep tiling: 64x64 tiles, 256 threads, 16 elems/thread (register-resident)
#define SB 64
#define NBSW (NN / SB)                      // 64
#define GRID_SW (NBSW * (NBSW + 1) / 2)     // 2080

typedef float v2f __attribute__((ext_vector_type(2)));

__device__ __forceinline__ float fexp2(float v) { return __builtin_amdgcn_exp2f(v); }

// DPP lane-shift add: no LDS/ds_bpermute latency (register-file crossing, ~2cy).
template <int CTRL>
__device__ __forceinline__ float dpp_add(float x) {
    int y = __builtin_amdgcn_update_dpp(0, __float_as_int(x), CTRL, 0xf, 0xf, true);
    return x + __int_as_float(y);
}
// Full wave64 sum; result lands in lane 63. Canonical gfx9 sequence.
__device__ __forceinline__ float wave_sum(float x) {
    x = dpp_add<0x111>(x);   // row_shr:1
    x = dpp_add<0x112>(x);   // row_shr:2
    x = dpp_add<0x114>(x);   // row_shr:4
    x = dpp_add<0x118>(x);   // row_shr:8  -> lane15 of each row16 = row sum
    x = dpp_add<0x142>(x);   // row_bcast:15
    x = dpp_add<0x143>(x);   // row_bcast:31 -> lane63 = wave sum
    return x;
}

// linear index -> (bi, bj) with bi <= bj, row-major over upper triangle
__device__ __forceinline__ void tri_decode(int t, int nb, int& bi, int& bj) {
    int b = 0, rem = t;
    while (rem >= nb - b) { rem -= nb - b; ++b; }   // uniform across block -> scalar
    bi = b; bj = b + rem;
}

// ---------------- ws layout (bytes) ----------------
// 0                       : double dist_sum
// 8                       : unsigned long long nz_count
// 16                      : double KL[NS]
// 16 + 8*NS               : double KK[NS]
// 16 + 16*NS              : float sq[NN]
// 16 + 16*NS + 4*NN       : float csig[NS]   (log2e / sigma_s^2)
// 16 + 16*NS + 4*NN + 4*NS: float copt

__global__ void k_rowsq(const float* __restrict__ x, float* __restrict__ sq,
                        double* __restrict__ dsum, unsigned long long* __restrict__ nzc) {
    int tid = blockIdx.x * blockDim.x + threadIdx.x;
    if (tid == 0) { *dsum = 0.0; *nzc = 0ull; }
    if (tid < NN) {
        const float4* row = (const float4*)(x + (size_t)tid * DD);
        float s = 0.f;
#pragma unroll
        for (int i = 0; i < DD / 4; ++i) {
            float4 v = row[i];
            s += v.x * v.x + v.y * v.y + v.z * v.z + v.w * v.w;
        }
        sq[tid] = s;
    }
}

// 128x128 output tile per block, upper-triangle grid, mirrored writes.
__launch_bounds__(256)
__global__ void k_d2(const float* __restrict__ x, const float* __restrict__ sq,
                     float* __restrict__ d2, double* __restrict__ dsum,
                     unsigned long long* __restrict__ nzc) {
    __shared__ float at[KCC][BT + 4];   // stride 132: 16B-aligned b128 reads, writes 4-way max
    __shared__ float btl[KCC][BT + 4];
    __shared__ double red_d[4];
    __shared__ int red_n[4];

    int bi, bj;
    tri_decode(blockIdx.x, NBD2, bi, bj);
    const int r0 = bi * BT, c0 = bj * BT;
    const int tid = threadIdx.x;
    const int tx = tid & 31;   // col group: 4 cols
    const int ty = tid >> 5;   // row group: 16 rows

    float acc[16][4];
#pragma unroll
    for (int r = 0; r < 16; ++r)
#pragma unroll
        for (int c = 0; c < 4; ++c) acc[r][c] = 0.f;

    for (int kb = 0; kb < DD; kb += KCC) {
#pragma unroll
        for (int i = 0; i < 4; ++i) {
            int idx = tid + 256 * i;       // 0..1023
            int row = idx >> 3;            // 0..127
            int k4 = (idx & 7) * 4;        // 0..28
            float4 va = *(const float4*)(x + (size_t)(r0 + row) * DD + kb + k4);
            at[k4 + 0][row] = va.x; at[k4 + 1][row] = va.y;
            at[k4 + 2][row] = va.z; at[k4 + 3][row] = va.w;
            float4 vb = *(const float4*)(x + (size_t)(c0 + row) * DD + kb + k4);
            btl[k4 + 0][row] = vb.x; btl[k4 + 1][row] = vb.y;
            btl[k4 + 2][row] = vb.z; btl[k4 + 3][row] = vb.w;
        }
        __syncthreads();
#pragma unroll
        for (int kk = 0; kk < KCC; ++kk) {
            float av[16];
            *(float4*)&av[0]  = *(const float4*)&at[kk][ty * 16 + 0];
            *(float4*)&av[4]  = *(const float4*)&at[kk][ty * 16 + 4];
            *(float4*)&av[8]  = *(const float4*)&at[kk][ty * 16 + 8];
            *(float4*)&av[12] = *(const float4*)&at[kk][ty * 16 + 12];
            float4 b4 = *(const float4*)&btl[kk][tx * 4];
            float bv[4] = {b4.x, b4.y, b4.z, b4.w};
#pragma unroll
            for (int r = 0; r < 16; ++r)
#pragma unroll
                for (int c = 0; c < 4; ++c)
                    acc[r][c] = fmaf(av[r], bv[c], acc[r][c]);
        }
        __syncthreads();
    }

    float sqi[16], sqj[4];
#pragma unroll
    for (int r = 0; r < 16; ++r) sqi[r] = sq[r0 + ty * 16 + r];
#pragma unroll
    for (int c = 0; c < 4; ++c) sqj[c] = sq[c0 + tx * 4 + c];

    float myd = 0.f;
    int myn = 0;
#pragma unroll
    for (int r = 0; r < 16; ++r) {
#pragma unroll
        for (int c = 0; c < 4; ++c) {
            float v = fmaxf(sqi[r] + sqj[c] - 2.f * acc[r][c], 0.f);
            acc[r][c] = v;
            if (v > 0.f) { myd += sqrtf(v); ++myn; }
        }
        float4 o = {acc[r][0], acc[r][1], acc[r][2], acc[r][3]};
        *(float4*)(d2 + (size_t)(r0 + ty * 16 + r) * NN + c0 + tx * 4) = o;
    }
    if (bi != bj) {
#pragma unroll
        for (int c = 0; c < 4; ++c) {
            size_t base = (size_t)(c0 + tx * 4 + c) * NN + r0 + ty * 16;
            float4 w0 = {acc[0][c],  acc[1][c],  acc[2][c],  acc[3][c]};
            float4 w1 = {acc[4][c],  acc[5][c],  acc[6][c],  acc[7][c]};
            float4 w2 = {acc[8][c],  acc[9][c],  acc[10][c], acc[11][c]};
            float4 w3 = {acc[12][c], acc[13][c], acc[14][c], acc[15][c]};
            *(float4*)(d2 + base + 0)  = w0;
            *(float4*)(d2 + base + 4)  = w1;
            *(float4*)(d2 + base + 8)  = w2;
            *(float4*)(d2 + base + 12) = w3;
        }
    }

    const int w = (bi == bj) ? 1 : 2;
    float sd = wave_sum(myd);
    float sn = wave_sum((float)myn);
    int wave = tid >> 6;
    if ((tid & 63) == 63) { red_d[wave] = (double)sd; red_n[wave] = (int)sn; }
    __syncthreads();
    if (tid == 0) {
        double td = red_d[0] + red_d[1] + red_d[2] + red_d[3];
        int tn = red_n[0] + red_n[1] + red_n[2] + red_n[3];
        atomicAdd(dsum, td * (double)w);
        atomicAdd(nzc, (unsigned long long)(tn * w));
    }
}

__global__ void k_sigmas(const double* __restrict__ dsum, const unsigned long long* __restrict__ nzc,
                         float* __restrict__ csig, double* __restrict__ KL, double* __restrict__ KK) {
    int t = threadIdx.x;
    float mean = (float)(*dsum / (double)(*nzc));
    float lo = 0.1f * mean;
    float hi = 10.0f * mean;
    float step = (hi - lo) / (float)NS;
    if (t < NS) {
        float s = lo + step * (float)t;
        csig[t] = (float)(1.4426950408889634 / ((double)s * (double)s));
        KL[t] = 0.0;
        KK[t] = 0.0;
    }
}

// Sweep v8 = R7 resident structure + DPP reduction (no ds_bpermute latency
// chains) + sigma constants forced to SGPR (readfirstlane) to cut VGPR live
// set. Data: 16 elems/thread loaded ONCE; CH=15 x 5 chunks over registers.
template <int CH, int NCHUNK>
__launch_bounds__(256, 3)
__global__ void k_sweep_all(const float* __restrict__ d2, const float* __restrict__ lk,
                            const float* __restrict__ csig, double* __restrict__ KL,
                            double* __restrict__ KK) {
    int bi, bj;
    tri_decode(blockIdx.x, NBSW, bi, bj);
    const int r0 = bi * SB, c0 = bj * SB;
    const float w = (bi == bj) ? 1.f : 2.f;

    const int rr = threadIdx.x >> 4;          // 0..15
    const int c4 = (threadIdx.x & 15) * 4;    // 0..60

    v2f nd[8], ll[8];                          // 32 VGPR, live across all chunks
#pragma unroll
    for (int it = 0; it < 4; ++it) {
        size_t off = (size_t)(r0 + rr + 16 * it) * NN + c0 + c4;
        float4 dv = *(const float4*)(d2 + off);
        float4 lv = *(const float4*)(lk + off);
        nd[it * 2 + 0] = (v2f){-dv.x, -dv.y};
        nd[it * 2 + 1] = (v2f){-dv.z, -dv.w};
        ll[it * 2 + 0] = (v2f){lv.x, lv.y};
        ll[it * 2 + 1] = (v2f){lv.z, lv.w};
    }

    __shared__ double part[4][2 * CH * NCHUNK];
    const int lane = threadIdx.x & 63, wave = threadIdx.x >> 6;

#pragma unroll 1
    for (int ch = 0; ch < NCHUNK; ++ch) {
        const int s0 = ch * CH;
        float c[CH];
#pragma unroll
        for (int s = 0; s < CH; ++s)   // force SGPR residency (frees 15 VGPRs)
            c[s] = __int_as_float(__builtin_amdgcn_readfirstlane(__float_as_int(csig[s0 + s])));
        v2f akl[CH], akk[CH];
#pragma unroll
        for (int s = 0; s < CH; ++s) { akl[s] = (v2f){0.f, 0.f}; akk[s] = (v2f){0.f, 0.f}; }

#pragma unroll
        for (int e = 0; e < 8; ++e) {
            v2f ndv = nd[e], L = ll[e];
#pragma unroll
            for (int s = 0; s < CH; ++s) {
                v2f arg = ndv * c[s];                               // v_pk_mul_f32 (1 SGPR ok)
                v2f K = {fexp2(arg.x), fexp2(arg.y)};               // 2x v_exp_f32
                akl[s] = __builtin_elementwise_fma(K, L, akl[s]);   // v_pk_fma_f32
                akk[s] = __builtin_elementwise_fma(K, K, akk[s]);
            }
        }

#pragma unroll
        for (int s = 0; s < CH; ++s) {
            float v1 = wave_sum(akl[s].x + akl[s].y);   // DPP: result in lane 63
            float v2 = wave_sum(akk[s].x + akk[s].y);
            if (lane == 63) {
                part[wave][2 * s0 + s]      = (double)(v1 * w);
                part[wave][2 * s0 + CH + s] = (double)(v2 * w);
            }
        }
    }
    __syncthreads();
    const int t = threadIdx.x;
    if (t < 2 * CH * NCHUNK) {
        double v = part[0][t] + part[1][t] + part[2][t] + part[3][t];
        const int ch = t / (2 * CH);          // compile-time divisor
        const int r  = t - ch * 2 * CH;
        if (r < CH) atomicAdd(&KL[ch * CH + r], v);
        else        atomicAdd(&KK[ch * CH + r - CH], v);
    }
}

__global__ void k_argmax(const double* __restrict__ KL, const double* __restrict__ KK,
                         const float* __restrict__ csig, float* __restrict__ copt) {
    if (threadIdx.x == 0 && blockIdx.x == 0) {
        double best = -1.0;
        int bi = 0;
        for (int i = 0; i < NS; ++i) {
            double loss = KL[i] / sqrt(KK[i]);
            if (loss > best) { best = loss; bi = i; }   // strict > keeps FIRST max (jnp.argmax)
        }
        *copt = csig[bi];
    }
}

__launch_bounds__(256)
__global__ void k_final(float* __restrict__ d2, const float* __restrict__ copt) {
    const float c = *copt;
    const float inv_n = 1.0f / (float)NN;
    const int nthreads = gridDim.x * blockDim.x;
    float4* p = (float4*)d2;
    for (int i = blockIdx.x * blockDim.x + threadIdx.x; i < TOT / 4; i += nthreads) {
        float4 v = p[i];
        v.x = fexp2(-v.x * c) * inv_n;
        v.y = fexp2(-v.y * c) * inv_n;
        v.z = fexp2(-v.z * c) * inv_n;
        v.w = fexp2(-v.w * c) * inv_n;
        p[i] = v;
    }
}

extern "C" void kernel_launch(void* const* d_in, const int* in_sizes, int n_in,
                              void* d_out, int out_size, void* d_ws, size_t ws_size,
                              hipStream_t stream) {
    const float* x  = (const float*)d_in[0];
    const float* lk = (const float*)d_in[1];
    float* out = (float*)d_out;   // doubles as the d2 buffer, transformed in place at the end
    char* ws = (char*)d_ws;

    double* dsum = (double*)(ws + 0);
    unsigned long long* nzc = (unsigned long long*)(ws + 8);
    double* KL = (double*)(ws + 16);
    double* KK = (double*)(ws + 16 + 8 * NS);
    float* sqv  = (float*)(ws + 16 + 16 * NS);
    float* csig = (float*)(ws + 16 + 16 * NS + 4 * NN);
    float* copt = (float*)(ws + 16 + 16 * NS + 4 * NN + 4 * NS);

    hipLaunchKernelGGL(k_rowsq, dim3(NN / 256), dim3(256), 0, stream, x, sqv, dsum, nzc);
    hipLaunchKernelGGL(k_d2, dim3(GRID_D2), dim3(256), 0, stream, x, sqv, out, dsum, nzc);
    hipLaunchKernelGGL(k_sigmas, dim3(1), dim3(128), 0, stream, dsum, nzc, csig, KL, KK);
    hipLaunchKernelGGL((k_sweep_all<15, 5>), dim3(GRID_SW), dim3(256), 0, stream, out, lk, csig, KL, KK);
    hipLaunchKernelGGL(k_argmax, dim3(1), dim3(64), 0, stream, KL, KK, csig, copt);
    hipLaunchKernelGGL(k_final, dim3(2048), dim3(256), 0, stream, out, copt);
}

// Round 12
// 183.804 us; speedup vs baseline: 1.7276x; 1.0312x over previous
//
#include <hip/hip_runtime.h>
#include <hip/hip_bf16.h>

#define NN 4096
#define DD 128
#define NS 75
#define TOT (NN * NN)

// k_d2 tiling
#define BT 128
#define KCC 32
#define NBD2 (NN / BT)                      // 32
#define GRID_D2 (NBD2 * (NBD2 + 1) / 2)     // 528

// sweep tiling: 64x64 tiles, 256 threads, 16 elems/thread (register-resident)
#define SB 64
#define NBSW (NN / SB)                      // 64
#define GRID_SW (NBSW * (NBSW + 1) / 2)     // 2080

typedef float v2f __attribute__((ext_vector_type(2)));

__device__ __forceinline__ float fexp2(float v) { return __builtin_amdgcn_exp2f(v); }

// DPP lane-shift add: no LDS/ds_bpermute latency (register-file crossing, ~2cy).
template <int CTRL>
__device__ __forceinline__ float dpp_add(float x) {
    int y = __builtin_amdgcn_update_dpp(0, __float_as_int(x), CTRL, 0xf, 0xf, true);
    return x + __int_as_float(y);
}
// Full wave64 sum; result lands in lane 63. Canonical gfx9 sequence.
__device__ __forceinline__ float wave_sum(float x) {
    x = dpp_add<0x111>(x);   // row_shr:1
    x = dpp_add<0x112>(x);   // row_shr:2
    x = dpp_add<0x114>(x);   // row_shr:4
    x = dpp_add<0x118>(x);   // row_shr:8  -> lane15 of each row16 = row sum
    x = dpp_add<0x142>(x);   // row_bcast:15
    x = dpp_add<0x143>(x);   // row_bcast:31 -> lane63 = wave sum
    return x;
}

// linear index -> (bi, bj) with bi <= bj, row-major over upper triangle
__device__ __forceinline__ void tri_decode(int t, int nb, int& bi, int& bj) {
    int b = 0, rem = t;
    while (rem >= nb - b) { rem -= nb - b; ++b; }   // uniform across block -> scalar
    bi = b; bj = b + rem;
}

// ---------------- ws layout (bytes) ----------------
#define WS_DSUM 0                      // double
#define WS_NZC  8                      // unsigned long long
#define WS_KL   16                     // double[32]  (slots 0..24 coarse, 25..29 refine)
#define WS_KK   (16 + 256)             // double[32]
#define WS_SQ   (16 + 512)             // float[NN]
#define WS_CSIG (WS_SQ + 4 * NN)       // float[NS]
#define WS_COPT (WS_CSIG + 512)        // float
#define WS_ZERO (WS_COPT + 4)          // int (always 0)
#define WS_W0   (WS_ZERO + 4)          // int (refine window base)

__global__ void k_rowsq(const float* __restrict__ x, float* __restrict__ sq,
                        double* __restrict__ dsum, unsigned long long* __restrict__ nzc) {
    int tid = blockIdx.x * blockDim.x + threadIdx.x;
    if (tid == 0) { *dsum = 0.0; *nzc = 0ull; }
    if (tid < NN) {
        const float4* row = (const float4*)(x + (size_t)tid * DD);
        float s = 0.f;
#pragma unroll
        for (int i = 0; i < DD / 4; ++i) {
            float4 v = row[i];
            s += v.x * v.x + v.y * v.y + v.z * v.z + v.w * v.w;
        }
        sq[tid] = s;
    }
}

// 128x128 output tile per block, upper-triangle grid, mirrored writes.
__launch_bounds__(256)
__global__ void k_d2(const float* __restrict__ x, const float* __restrict__ sq,
                     float* __restrict__ d2, double* __restrict__ dsum,
                     unsigned long long* __restrict__ nzc) {
    __shared__ float at[KCC][BT + 4];   // stride 132: 16B-aligned b128 reads, writes 4-way max
    __shared__ float btl[KCC][BT + 4];
    __shared__ double red_d[4];
    __shared__ int red_n[4];

    int bi, bj;
    tri_decode(blockIdx.x, NBD2, bi, bj);
    const int r0 = bi * BT, c0 = bj * BT;
    const int tid = threadIdx.x;
    const int tx = tid & 31;   // col group: 4 cols
    const int ty = tid >> 5;   // row group: 16 rows

    float acc[16][4];
#pragma unroll
    for (int r = 0; r < 16; ++r)
#pragma unroll
        for (int c = 0; c < 4; ++c) acc[r][c] = 0.f;

    for (int kb = 0; kb < DD; kb += KCC) {
#pragma unroll
        for (int i = 0; i < 4; ++i) {
            int idx = tid + 256 * i;       // 0..1023
            int row = idx >> 3;            // 0..127
            int k4 = (idx & 7) * 4;        // 0..28
            float4 va = *(const float4*)(x + (size_t)(r0 + row) * DD + kb + k4);
            at[k4 + 0][row] = va.x; at[k4 + 1][row] = va.y;
            at[k4 + 2][row] = va.z; at[k4 + 3][row] = va.w;
            float4 vb = *(const float4*)(x + (size_t)(c0 + row) * DD + kb + k4);
            btl[k4 + 0][row] = vb.x; btl[k4 + 1][row] = vb.y;
            btl[k4 + 2][row] = vb.z; btl[k4 + 3][row] = vb.w;
        }
        __syncthreads();
#pragma unroll
        for (int kk = 0; kk < KCC; ++kk) {
            float av[16];
            *(float4*)&av[0]  = *(const float4*)&at[kk][ty * 16 + 0];
            *(float4*)&av[4]  = *(const float4*)&at[kk][ty * 16 + 4];
            *(float4*)&av[8]  = *(const float4*)&at[kk][ty * 16 + 8];
            *(float4*)&av[12] = *(const float4*)&at[kk][ty * 16 + 12];
            float4 b4 = *(const float4*)&btl[kk][tx * 4];
            float bv[4] = {b4.x, b4.y, b4.z, b4.w};
#pragma unroll
            for (int r = 0; r < 16; ++r)
#pragma unroll
                for (int c = 0; c < 4; ++c)
                    acc[r][c] = fmaf(av[r], bv[c], acc[r][c]);
        }
        __syncthreads();
    }

    float sqi[16], sqj[4];
#pragma unroll
    for (int r = 0; r < 16; ++r) sqi[r] = sq[r0 + ty * 16 + r];
#pragma unroll
    for (int c = 0; c < 4; ++c) sqj[c] = sq[c0 + tx * 4 + c];

    float myd = 0.f;
    int myn = 0;
#pragma unroll
    for (int r = 0; r < 16; ++r) {
#pragma unroll
        for (int c = 0; c < 4; ++c) {
            float v = fmaxf(sqi[r] + sqj[c] - 2.f * acc[r][c], 0.f);
            acc[r][c] = v;
            if (v > 0.f) { myd += sqrtf(v); ++myn; }
        }
        float4 o = {acc[r][0], acc[r][1], acc[r][2], acc[r][3]};
        *(float4*)(d2 + (size_t)(r0 + ty * 16 + r) * NN + c0 + tx * 4) = o;
    }
    if (bi != bj) {
#pragma unroll
        for (int c = 0; c < 4; ++c) {
            size_t base = (size_t)(c0 + tx * 4 + c) * NN + r0 + ty * 16;
            float4 w0 = {acc[0][c],  acc[1][c],  acc[2][c],  acc[3][c]};
            float4 w1 = {acc[4][c],  acc[5][c],  acc[6][c],  acc[7][c]};
            float4 w2 = {acc[8][c],  acc[9][c],  acc[10][c], acc[11][c]};
            float4 w3 = {acc[12][c], acc[13][c], acc[14][c], acc[15][c]};
            *(float4*)(d2 + base + 0)  = w0;
            *(float4*)(d2 + base + 4)  = w1;
            *(float4*)(d2 + base + 8)  = w2;
            *(float4*)(d2 + base + 12) = w3;
        }
    }

    const int w = (bi == bj) ? 1 : 2;
    float sd = wave_sum(myd);
    float sn = wave_sum((float)myn);
    int wave = tid >> 6;
    if ((tid & 63) == 63) { red_d[wave] = (double)sd; red_n[wave] = (int)sn; }
    __syncthreads();
    if (tid == 0) {
        double td = red_d[0] + red_d[1] + red_d[2] + red_d[3];
        int tn = red_n[0] + red_n[1] + red_n[2] + red_n[3];
        atomicAdd(dsum, td * (double)w);
        atomicAdd(nzc, (unsigned long long)(tn * w));
    }
}

__global__ void k_sigmas(const double* __restrict__ dsum, const unsigned long long* __restrict__ nzc,
                         float* __restrict__ csig, double* __restrict__ KL, double* __restrict__ KK,
                         int* __restrict__ zero_) {
    int t = threadIdx.x;
    float mean = (float)(*dsum / (double)(*nzc));
    float lo = 0.1f * mean;
    float hi = 10.0f * mean;
    float step = (hi - lo) / (float)NS;
    if (t < NS) {
        float s = lo + step * (float)t;
        csig[t] = (float)(1.4426950408889634 / ((double)s * (double)s));
    }
    if (t < 32) { KL[t] = 0.0; KK[t] = 0.0; }
    if (t == 96) *zero_ = 0;
}

// Sweep: 64x64 tile, 16 elems/thread resident, DPP reduction, SGPR sigmas.
// Evaluates CH*NCHUNK sigmas at indices s0 + STRIDE*k (s0 read from memory),
// accumulating into KL/KK slots SLOT0+k. Coarse: <5,5,3,0> s0=0 -> sigmas
// 0,3,..,72. Refine: <5,1,1,25> s0=w0 -> sigmas w0..w0+4.
template <int CH, int NCHUNK, int STRIDE, int SLOT0>
__launch_bounds__(256, 4)
__global__ void k_sweep(const float* __restrict__ d2, const float* __restrict__ lk,
                        const float* __restrict__ csig, double* __restrict__ KL,
                        double* __restrict__ KK, const int* __restrict__ s0ptr) {
    int bi, bj;
    tri_decode(blockIdx.x, NBSW, bi, bj);
    const int r0 = bi * SB, c0 = bj * SB;
    const float w = (bi == bj) ? 1.f : 2.f;
    const int s0 = *s0ptr;

    const int rr = threadIdx.x >> 4;          // 0..15
    const int c4 = (threadIdx.x & 15) * 4;    // 0..60

    v2f nd[8], ll[8];                          // 32 VGPR, live across all chunks
#pragma unroll
    for (int it = 0; it < 4; ++it) {
        size_t off = (size_t)(r0 + rr + 16 * it) * NN + c0 + c4;
        float4 dv = *(const float4*)(d2 + off);
        float4 lv = *(const float4*)(lk + off);
        nd[it * 2 + 0] = (v2f){-dv.x, -dv.y};
        nd[it * 2 + 1] = (v2f){-dv.z, -dv.w};
        ll[it * 2 + 0] = (v2f){lv.x, lv.y};
        ll[it * 2 + 1] = (v2f){lv.z, lv.w};
    }

    __shared__ double part[4][2 * CH * NCHUNK];
    const int lane = threadIdx.x & 63, wave = threadIdx.x >> 6;

#pragma unroll 1
    for (int ch = 0; ch < NCHUNK; ++ch) {
        float c[CH];
#pragma unroll
        for (int s = 0; s < CH; ++s)   // force SGPR residency
            c[s] = __int_as_float(__builtin_amdgcn_readfirstlane(
                       __float_as_int(csig[s0 + STRIDE * (ch * CH + s)])));
        v2f akl[CH], akk[CH];
#pragma unroll
        for (int s = 0; s < CH; ++s) { akl[s] = (v2f){0.f, 0.f}; akk[s] = (v2f){0.f, 0.f}; }

#pragma unroll
        for (int e = 0; e < 8; ++e) {
            v2f ndv = nd[e], L = ll[e];
#pragma unroll
            for (int s = 0; s < CH; ++s) {
                v2f arg = ndv * c[s];                               // v_pk_mul_f32
                v2f K = {fexp2(arg.x), fexp2(arg.y)};               // 2x v_exp_f32
                akl[s] = __builtin_elementwise_fma(K, L, akl[s]);   // v_pk_fma_f32
                akk[s] = __builtin_elementwise_fma(K, K, akk[s]);
            }
        }

#pragma unroll
        for (int s = 0; s < CH; ++s) {
            float v1 = wave_sum(akl[s].x + akl[s].y);   // DPP: result in lane 63
            float v2 = wave_sum(akk[s].x + akk[s].y);
            if (lane == 63) {
                part[wave][2 * (ch * CH) + s]      = (double)(v1 * w);
                part[wave][2 * (ch * CH) + CH + s] = (double)(v2 * w);
            }
        }
    }
    __syncthreads();
    const int t = threadIdx.x;
    if (t < 2 * CH * NCHUNK) {
        double v = part[0][t] + part[1][t] + part[2][t] + part[3][t];
        const int ch = t / (2 * CH);
        const int r  = t - ch * 2 * CH;
        if (r < CH) atomicAdd(&KL[SLOT0 + ch * CH + r], v);
        else        atomicAdd(&KK[SLOT0 + ch * CH + r - CH], v);
    }
}

// coarse winner -> refine window base. Peak of a unimodal curve sampled at
// stride 3 lies in (s_c-3, s_c+3) -> integer window [s_c-2, s_c+2], clamped.
__global__ void k_coarse_argmax(const double* __restrict__ KL, const double* __restrict__ KK,
                                int* __restrict__ w0) {
    if (threadIdx.x == 0) {
        double best = -1.0;
        int bk = 0;
        for (int k = 0; k < 25; ++k) {
            double loss = KL[k] / sqrt(KK[k]);
            if (loss > best) { best = loss; bk = k; }
        }
        int sc = 3 * bk;
        int wv = sc - 2;
        if (wv < 0) wv = 0;
        if (wv > NS - 5) wv = NS - 5;
        *w0 = wv;
    }
}

__global__ void k_refine_argmax(const double* __restrict__ KL, const double* __restrict__ KK,
                                const float* __restrict__ csig, const int* __restrict__ w0p,
                                float* __restrict__ copt) {
    if (threadIdx.x == 0) {
        double best = -1.0;
        int bk = 0;
        for (int k = 0; k < 5; ++k) {
            double loss = KL[25 + k] / sqrt(KK[25 + k]);
            if (loss > best) { best = loss; bk = k; }   // strict > = first max
        }
        *copt = csig[*w0p + bk];
    }
}

// Final: A = exp2(-d2*c)/n, upper-triangle blocks, mirror-written (halves reads).
__launch_bounds__(256)
__global__ void k_final(float* __restrict__ d2, const float* __restrict__ copt) {
    const float cc = *copt;
    const float inv_n = 1.0f / (float)NN;
    int bi, bj;
    tri_decode(blockIdx.x, NBD2, bi, bj);
    const int r0 = bi * BT, c0 = bj * BT;
    const int tx = threadIdx.x & 31, ty = threadIdx.x >> 5;

    float a[16][4];
#pragma unroll
    for (int r = 0; r < 16; ++r) {
        size_t off = (size_t)(r0 + ty * 16 + r) * NN + c0 + tx * 4;
        float4 v = *(const float4*)(d2 + off);
        a[r][0] = fexp2(-v.x * cc) * inv_n;
        a[r][1] = fexp2(-v.y * cc) * inv_n;
        a[r][2] = fexp2(-v.z * cc) * inv_n;
        a[r][3] = fexp2(-v.w * cc) * inv_n;
        float4 o = {a[r][0], a[r][1], a[r][2], a[r][3]};
        *(float4*)(d2 + off) = o;
    }
    if (bi != bj) {
#pragma unroll
        for (int c = 0; c < 4; ++c) {
            size_t base = (size_t)(c0 + tx * 4 + c) * NN + r0 + ty * 16;
            float4 w0 = {a[0][c],  a[1][c],  a[2][c],  a[3][c]};
            float4 w1 = {a[4][c],  a[5][c],  a[6][c],  a[7][c]};
            float4 w2 = {a[8][c],  a[9][c],  a[10][c], a[11][c]};
            float4 w3 = {a[12][c], a[13][c], a[14][c], a[15][c]};
            *(float4*)(d2 + base + 0)  = w0;
            *(float4*)(d2 + base + 4)  = w1;
            *(float4*)(d2 + base + 8)  = w2;
            *(float4*)(d2 + base + 12) = w3;
        }
    }
}

extern "C" void kernel_launch(void* const* d_in, const int* in_sizes, int n_in,
                              void* d_out, int out_size, void* d_ws, size_t ws_size,
                              hipStream_t stream) {
    const float* x  = (const float*)d_in[0];
    const float* lk = (const float*)d_in[1];
    float* out = (float*)d_out;   // doubles as the d2 buffer, transformed in place at the end
    char* ws = (char*)d_ws;

    double* dsum = (double*)(ws + WS_DSUM);
    unsigned long long* nzc = (unsigned long long*)(ws + WS_NZC);
    double* KL = (double*)(ws + WS_KL);
    double* KK = (double*)(ws + WS_KK);
    float* sqv  = (float*)(ws + WS_SQ);
    float* csig = (float*)(ws + WS_CSIG);
    float* copt = (float*)(ws + WS_COPT);
    int* zero_  = (int*)(ws + WS_ZERO);
    int* w0_    = (int*)(ws + WS_W0);

    hipLaunchKernelGGL(k_rowsq, dim3(NN / 256), dim3(256), 0, stream, x, sqv, dsum, nzc);
    hipLaunchKernelGGL(k_d2, dim3(GRID_D2), dim3(256), 0, stream, x, sqv, out, dsum, nzc);
    hipLaunchKernelGGL(k_sigmas, dim3(1), dim3(128), 0, stream, dsum, nzc, csig, KL, KK, zero_);
    hipLaunchKernelGGL((k_sweep<5, 5, 3, 0>), dim3(GRID_SW), dim3(256), 0, stream,
                       out, lk, csig, KL, KK, zero_);
    hipLaunchKernelGGL(k_coarse_argmax, dim3(1), dim3(64), 0, stream, KL, KK, w0_);
    hipLaunchKernelGGL((k_sweep<5, 1, 1, 25>), dim3(GRID_SW), dim3(256), 0, stream,
                       out, lk, csig, KL, KK, w0_);
    hipLaunchKernelGGL(k_refine_argmax, dim3(1), dim3(64), 0, stream, KL, KK, csig, w0_, copt);
    hipLaunchKernelGGL(k_final, dim3(GRID_D2), dim3(256), 0, stream, out, copt);
}

// Round 13
// 177.035 us; speedup vs baseline: 1.7937x; 1.0382x over previous
//
#include <hip/hip_runtime.h>
#include <hip/hip_bf16.h>

#define NN 4096
#define DD 128
#define NS 75
#define TOT (NN * NN)

// k_d2 tiling (MFMA): 128x128 block, 4 waves, 64x64 per wave
#define BT 128
#define NBD2 (NN / BT)                      // 32
#define GRID_D2 (NBD2 * (NBD2 + 1) / 2)     // 528

// sweep tiling: 64x64 tiles, 256 threads, 16 elems/thread (register-resident)
#define SB 64
#define NBSW (NN / SB)                      // 64
#define GRID_SW (NBSW * (NBSW + 1) / 2)     // 2080

typedef float v2f __attribute__((ext_vector_type(2)));
typedef float f32x4 __attribute__((ext_vector_type(4)));
typedef short bf16x8 __attribute__((ext_vector_type(8)));

__device__ __forceinline__ float fexp2(float v) { return __builtin_amdgcn_exp2f(v); }

// DPP lane-shift add: no LDS/ds_bpermute latency (register-file crossing, ~2cy).
template <int CTRL>
__device__ __forceinline__ float dpp_add(float x) {
    int y = __builtin_amdgcn_update_dpp(0, __float_as_int(x), CTRL, 0xf, 0xf, true);
    return x + __int_as_float(y);
}
// Full wave64 sum; result lands in lane 63. Canonical gfx9 sequence.
__device__ __forceinline__ float wave_sum(float x) {
    x = dpp_add<0x111>(x);   // row_shr:1
    x = dpp_add<0x112>(x);   // row_shr:2
    x = dpp_add<0x114>(x);   // row_shr:4
    x = dpp_add<0x118>(x);   // row_shr:8  -> lane15 of each row16 = row sum
    x = dpp_add<0x142>(x);   // row_bcast:15
    x = dpp_add<0x143>(x);   // row_bcast:31 -> lane63 = wave sum
    return x;
}

// linear index -> (bi, bj) with bi <= bj, row-major over upper triangle
__device__ __forceinline__ void tri_decode(int t, int nb, int& bi, int& bj) {
    int b = 0, rem = t;
    while (rem >= nb - b) { rem -= nb - b; ++b; }   // uniform across block -> scalar
    bi = b; bj = b + rem;
}

// Split f32 -> bf16 hi (bit-truncate, top 16 bits) + bf16 lo (truncate of exact
// residual). x ~= hi + lo with |err| <= 2^-14 |x|; G error << d2 tolerance.
__device__ __forceinline__ void cvt_split(const float4& v0, const float4& v1,
                                          bf16x8& hi, bf16x8& lo) {
    float f[8] = {v0.x, v0.y, v0.z, v0.w, v1.x, v1.y, v1.z, v1.w};
#pragma unroll
    for (int j = 0; j < 8; ++j) {
        unsigned b = __float_as_uint(f[j]);
        hi[j] = (short)(b >> 16);
        float l = f[j] - __uint_as_float(b & 0xFFFF0000u);   // exact residual
        lo[j] = (short)(__float_as_uint(l) >> 16);
    }
}

// ---------------- ws layout (bytes) ----------------
#define WS_DSUM 0                      // double
#define WS_NZC  8                      // unsigned long long
#define WS_KL   16                     // double[32]  (slots 0..24 coarse, 25..29 refine)
#define WS_KK   (16 + 256)             // double[32]
#define WS_SQ   (16 + 512)             // float[NN]
#define WS_CSIG (WS_SQ + 4 * NN)       // float[NS]
#define WS_COPT (WS_CSIG + 512)        // float
#define WS_ZERO (WS_COPT + 4)          // int (always 0)
#define WS_W0   (WS_ZERO + 4)          // int (refine window base)

__global__ void k_rowsq(const float* __restrict__ x, float* __restrict__ sq,
                        double* __restrict__ dsum, unsigned long long* __restrict__ nzc) {
    int tid = blockIdx.x * blockDim.x + threadIdx.x;
    if (tid == 0) { *dsum = 0.0; *nzc = 0ull; }
    if (tid < NN) {
        const float4* row = (const float4*)(x + (size_t)tid * DD);
        float s = 0.f;
#pragma unroll
        for (int i = 0; i < DD / 4; ++i) {
            float4 v = row[i];
            s += v.x * v.x + v.y * v.y + v.z * v.z + v.w * v.w;
        }
        sq[tid] = s;
    }
}

// d2 via split-bf16 MFMA: G = hi.hi^T + hi.lo^T + lo.hi^T (lo.lo dropped).
// No LDS staging: fragments converted on the fly from L2-hot x (2 MB).
// A-frag: row = l&15, k = (l>>4)*8 + r. B-frag: col = l&15, same k (mirror).
// C/D (m89-verified): row(M) = (l>>4)*4 + reg, col(N) = l&15.
__launch_bounds__(256)
__global__ void k_d2(const float* __restrict__ x, const float* __restrict__ sq,
                     float* __restrict__ d2, double* __restrict__ dsum,
                     unsigned long long* __restrict__ nzc) {
    __shared__ double red_d[4];
    __shared__ int red_n[4];

    int bi, bj;
    tri_decode(blockIdx.x, NBD2, bi, bj);
    const int r0 = bi * BT, c0 = bj * BT;
    const int tid = threadIdx.x;
    const int l  = tid & 63, wid = tid >> 6;
    const int wr = wid >> 1, wc = wid & 1;    // wave tile: 64x64
    const int lr = l & 15;                    // A-row / B-col / D-col component
    const int lk = (l >> 4) * 8;              // k base within 32-chunk
    const int l4 = (l >> 4) * 4;              // D-row base

    const int ar = r0 + wr * 64 + lr;         // + a*16 = A fragment rows
    const int br = c0 + wc * 64 + lr;         // + b*16 = B fragment rows (of x)

    f32x4 acc[4][4];
#pragma unroll
    for (int a = 0; a < 4; ++a)
#pragma unroll
        for (int b = 0; b < 4; ++b) acc[a][b] = (f32x4){0.f, 0.f, 0.f, 0.f};

#pragma unroll 1
    for (int kc = 0; kc < 4; ++kc) {
        const int k0 = kc * 32 + lk;
        bf16x8 ah[4], al[4], bh[4], bl[4];
#pragma unroll
        for (int t = 0; t < 4; ++t) {
            const float* pa = x + (size_t)(ar + t * 16) * DD + k0;
            float4 a0 = *(const float4*)pa;
            float4 a1 = *(const float4*)(pa + 4);
            cvt_split(a0, a1, ah[t], al[t]);
            const float* pb = x + (size_t)(br + t * 16) * DD + k0;
            float4 b0 = *(const float4*)pb;
            float4 b1 = *(const float4*)(pb + 4);
            cvt_split(b0, b1, bh[t], bl[t]);
        }
#pragma unroll
        for (int a = 0; a < 4; ++a)
#pragma unroll
            for (int b = 0; b < 4; ++b) {
                acc[a][b] = __builtin_amdgcn_mfma_f32_16x16x32_bf16(ah[a], bh[b], acc[a][b], 0, 0, 0);
                acc[a][b] = __builtin_amdgcn_mfma_f32_16x16x32_bf16(ah[a], bl[b], acc[a][b], 0, 0, 0);
                acc[a][b] = __builtin_amdgcn_mfma_f32_16x16x32_bf16(al[a], bh[b], acc[a][b], 0, 0, 0);
            }
    }

    // Epilogue: d2 = max(sq_r + sq_c - 2G, 0); direct (coalesced 64B groups)
    // + float4 mirror for off-diagonal blocks; dist-sum/nnz reduction.
    float myd = 0.f;
    int myn = 0;
#pragma unroll
    for (int a = 0; a < 4; ++a) {
        const int grb = r0 + wr * 64 + a * 16 + l4;        // D rows grb..grb+3
        float4 sqr = *(const float4*)(sq + grb);
        float sr[4] = {sqr.x, sqr.y, sqr.z, sqr.w};
#pragma unroll
        for (int b = 0; b < 4; ++b) {
            const int gc = c0 + wc * 64 + b * 16 + lr;     // D col
            const float sc = sq[gc];
            float dv[4];
#pragma unroll
            for (int v = 0; v < 4; ++v) {
                float d = fmaxf(sr[v] + sc - 2.f * acc[a][b][v], 0.f);
                dv[v] = d;
                if (d > 0.f) { myd += sqrtf(d); ++myn; }
                d2[(size_t)(grb + v) * NN + gc] = d;
            }
            if (bi != bj) {
                float4 o = {dv[0], dv[1], dv[2], dv[3]};
                *(float4*)(d2 + (size_t)gc * NN + grb) = o;
            }
        }
    }

    const int w = (bi == bj) ? 1 : 2;
    float sd = wave_sum(myd);
    float sn = wave_sum((float)myn);
    if ((tid & 63) == 63) { red_d[wid] = (double)sd; red_n[wid] = (int)sn; }
    __syncthreads();
    if (tid == 0) {
        double td = red_d[0] + red_d[1] + red_d[2] + red_d[3];
        int tn = red_n[0] + red_n[1] + red_n[2] + red_n[3];
        atomicAdd(dsum, td * (double)w);
        atomicAdd(nzc, (unsigned long long)(tn * w));
    }
}

__global__ void k_sigmas(const double* __restrict__ dsum, const unsigned long long* __restrict__ nzc,
                         float* __restrict__ csig, double* __restrict__ KL, double* __restrict__ KK,
                         int* __restrict__ zero_) {
    int t = threadIdx.x;
    float mean = (float)(*dsum / (double)(*nzc));
    float lo = 0.1f * mean;
    float hi = 10.0f * mean;
    float step = (hi - lo) / (float)NS;
    if (t < NS) {
        float s = lo + step * (float)t;
        csig[t] = (float)(1.4426950408889634 / ((double)s * (double)s));
    }
    if (t < 32) { KL[t] = 0.0; KK[t] = 0.0; }
    if (t == 96) *zero_ = 0;
}

// Sweep: 64x64 tile, 16 elems/thread resident, DPP reduction, SGPR sigmas.
// Evaluates CH*NCHUNK sigmas at indices s0 + STRIDE*k, into slots SLOT0+k.
template <int CH, int NCHUNK, int STRIDE, int SLOT0>
__launch_bounds__(256, 4)
__global__ void k_sweep(const float* __restrict__ d2, const float* __restrict__ lk,
                        const float* __restrict__ csig, double* __restrict__ KL,
                        double* __restrict__ KK, const int* __restrict__ s0ptr) {
    int bi, bj;
    tri_decode(blockIdx.x, NBSW, bi, bj);
    const int r0 = bi * SB, c0 = bj * SB;
    const float w = (bi == bj) ? 1.f : 2.f;
    const int s0 = *s0ptr;

    const int rr = threadIdx.x >> 4;          // 0..15
    const int c4 = (threadIdx.x & 15) * 4;    // 0..60

    v2f nd[8], ll[8];                          // 32 VGPR, live across all chunks
#pragma unroll
    for (int it = 0; it < 4; ++it) {
        size_t off = (size_t)(r0 + rr + 16 * it) * NN + c0 + c4;
        float4 dv = *(const float4*)(d2 + off);
        float4 lv = *(const float4*)(lk + off);
        nd[it * 2 + 0] = (v2f){-dv.x, -dv.y};
        nd[it * 2 + 1] = (v2f){-dv.z, -dv.w};
        ll[it * 2 + 0] = (v2f){lv.x, lv.y};
        ll[it * 2 + 1] = (v2f){lv.z, lv.w};
    }

    __shared__ double part[4][2 * CH * NCHUNK];
    const int lane = threadIdx.x & 63, wave = threadIdx.x >> 6;

#pragma unroll 1
    for (int ch = 0; ch < NCHUNK; ++ch) {
        float c[CH];
#pragma unroll
        for (int s = 0; s < CH; ++s)   // force SGPR residency
            c[s] = __int_as_float(__builtin_amdgcn_readfirstlane(
                       __float_as_int(csig[s0 + STRIDE * (ch * CH + s)])));
        v2f akl[CH], akk[CH];
#pragma unroll
        for (int s = 0; s < CH; ++s) { akl[s] = (v2f){0.f, 0.f}; akk[s] = (v2f){0.f, 0.f}; }

#pragma unroll
        for (int e = 0; e < 8; ++e) {
            v2f ndv = nd[e], L = ll[e];
#pragma unroll
            for (int s = 0; s < CH; ++s) {
                v2f arg = ndv * c[s];                               // v_pk_mul_f32
                v2f K = {fexp2(arg.x), fexp2(arg.y)};               // 2x v_exp_f32
                akl[s] = __builtin_elementwise_fma(K, L, akl[s]);   // v_pk_fma_f32
                akk[s] = __builtin_elementwise_fma(K, K, akk[s]);
            }
        }

#pragma unroll
        for (int s = 0; s < CH; ++s) {
            float v1 = wave_sum(akl[s].x + akl[s].y);   // DPP: result in lane 63
            float v2 = wave_sum(akk[s].x + akk[s].y);
            if (lane == 63) {
                part[wave][2 * (ch * CH) + s]      = (double)(v1 * w);
                part[wave][2 * (ch * CH) + CH + s] = (double)(v2 * w);
            }
        }
    }
    __syncthreads();
    const int t = threadIdx.x;
    if (t < 2 * CH * NCHUNK) {
        double v = part[0][t] + part[1][t] + part[2][t] + part[3][t];
        const int ch = t / (2 * CH);
        const int r  = t - ch * 2 * CH;
        if (r < CH) atomicAdd(&KL[SLOT0 + ch * CH + r], v);
        else        atomicAdd(&KK[SLOT0 + ch * CH + r - CH], v);
    }
}

// coarse winner -> refine window base. Peak of a unimodal curve sampled at
// stride 3 lies in (s_c-3, s_c+3) -> integer window [s_c-2, s_c+2], clamped.
__global__ void k_coarse_argmax(const double* __restrict__ KL, const double* __restrict__ KK,
                                int* __restrict__ w0) {
    if (threadIdx.x == 0) {
        double best = -1.0;
        int bk = 0;
        for (int k = 0; k < 25; ++k) {
            double loss = KL[k] / sqrt(KK[k]);
            if (loss > best) { best = loss; bk = k; }
        }
        int sc = 3 * bk;
        int wv = sc - 2;
        if (wv < 0) wv = 0;
        if (wv > NS - 5) wv = NS - 5;
        *w0 = wv;
    }
}

__global__ void k_refine_argmax(const double* __restrict__ KL, const double* __restrict__ KK,
                                const float* __restrict__ csig, const int* __restrict__ w0p,
                                float* __restrict__ copt) {
    if (threadIdx.x == 0) {
        double best = -1.0;
        int bk = 0;
        for (int k = 0; k < 5; ++k) {
            double loss = KL[25 + k] / sqrt(KK[25 + k]);
            if (loss > best) { best = loss; bk = k; }   // strict > = first max
        }
        *copt = csig[*w0p + bk];
    }
}

// Final: A = exp2(-d2*c)/n, upper-triangle blocks, mirror-written (halves reads).
__launch_bounds__(256)
__global__ void k_final(float* __restrict__ d2, const float* __restrict__ copt) {
    const float cc = *copt;
    const float inv_n = 1.0f / (float)NN;
    int bi, bj;
    tri_decode(blockIdx.x, NBD2, bi, bj);
    const int r0 = bi * BT, c0 = bj * BT;
    const int tx = threadIdx.x & 31, ty = threadIdx.x >> 5;

    float a[16][4];
#pragma unroll
    for (int r = 0; r < 16; ++r) {
        size_t off = (size_t)(r0 + ty * 16 + r) * NN + c0 + tx * 4;
        float4 v = *(const float4*)(d2 + off);
        a[r][0] = fexp2(-v.x * cc) * inv_n;
        a[r][1] = fexp2(-v.y * cc) * inv_n;
        a[r][2] = fexp2(-v.z * cc) * inv_n;
        a[r][3] = fexp2(-v.w * cc) * inv_n;
        float4 o = {a[r][0], a[r][1], a[r][2], a[r][3]};
        *(float4*)(d2 + off) = o;
    }
    if (bi != bj) {
#pragma unroll
        for (int c = 0; c < 4; ++c) {
            size_t base = (size_t)(c0 + tx * 4 + c) * NN + r0 + ty * 16;
            float4 w0 = {a[0][c],  a[1][c],  a[2][c],  a[3][c]};
            float4 w1 = {a[4][c],  a[5][c],  a[6][c],  a[7][c]};
            float4 w2 = {a[8][c],  a[9][c],  a[10][c], a[11][c]};
            float4 w3 = {a[12][c], a[13][c], a[14][c], a[15][c]};
            *(float4*)(d2 + base + 0)  = w0;
            *(float4*)(d2 + base + 4)  = w1;
            *(float4*)(d2 + base + 8)  = w2;
            *(float4*)(d2 + base + 12) = w3;
        }
    }
}

extern "C" void kernel_launch(void* const* d_in, const int* in_sizes, int n_in,
                              void* d_out, int out_size, void* d_ws, size_t ws_size,
                              hipStream_t stream) {
    const float* x  = (const float*)d_in[0];
    const float* lk = (const float*)d_in[1];
    float* out = (float*)d_out;   // doubles as the d2 buffer, transformed in place at the end
    char* ws = (char*)d_ws;

    double* dsum = (double*)(ws + WS_DSUM);
    unsigned long long* nzc = (unsigned long long*)(ws + WS_NZC);
    double* KL = (double*)(ws + WS_KL);
    double* KK = (double*)(ws + WS_KK);
    float* sqv  = (float*)(ws + WS_SQ);
    float* csig = (float*)(ws + WS_CSIG);
    float* copt = (float*)(ws + WS_COPT);
    int* zero_  = (int*)(ws + WS_ZERO);
    int* w0_    = (int*)(ws + WS_W0);

    hipLaunchKernelGGL(k_rowsq, dim3(NN / 256), dim3(256), 0, stream, x, sqv, dsum, nzc);
    hipLaunchKernelGGL(k_d2, dim3(GRID_D2), dim3(256), 0, stream, x, sqv, out, dsum, nzc);
    hipLaunchKernelGGL(k_sigmas, dim3(1), dim3(128), 0, stream, dsum, nzc, csig, KL, KK, zero_);
    hipLaunchKernelGGL((k_sweep<5, 5, 3, 0>), dim3(GRID_SW), dim3(256), 0, stream,
                       out, lk, csig, KL, KK, zero_);
    hipLaunchKernelGGL(k_coarse_argmax, dim3(1), dim3(64), 0, stream, KL, KK, w0_);
    hipLaunchKernelGGL((k_sweep<5, 1, 1, 25>), dim3(GRID_SW), dim3(256), 0, stream,
                       out, lk, csig, KL, KK, w0_);
    hipLaunchKernelGGL(k_refine_argmax, dim3(1), dim3(64), 0, stream, KL, KK, csig, w0_, copt);
    hipLaunchKernelGGL(k_final, dim3(GRID_D2), dim3(256), 0, stream, out, copt);
}